// Round 7
// baseline (267.233 us; speedup 1.0000x reference)
//
#include <hip/hip_runtime.h>
#include <hip/hip_bf16.h>

// LocallyConnected2d: y[b,o,h,w] = bias[o,h,w] +
//   sum_{i,kh,kw} xpad[b,i,h+kh,w+kw] * weight[i,o,h,w,kh,kw]
// B=64, CIN=COUT=64, H=W=32, K=3, pad=1, fp32 in/out.
// Round 12: BARRIER-FREE fused kernel. Key fact: B-frag for chunk c, frag nt,
// lane l (quad=l>>4, col=l&15) = w[4c+quad][obase+nt*16+col][loc][kk=0..7] —
// 9 consecutive floats in the native weight layout. So each lane loads its
// own B-frag directly (2xfloat4+dword, unaligned-safe) and f2bf's it:
// issueW/scatterW/Bf deleted. kk=8 (same cache line) goes to the verified Bs
// layout via 2 wave-private ds_write_b16/chunk (producer: chunk i>>2, lane
// quad=i&3 writes slot ((ll*2+i>>5)*2+nt, (i&31)>>3)*16+col, i&7)).
// scr4 (A transpose, verified round 10/11) and Bs are wave-private ->
// NO barriers anywhere. LDS 49->33KB. Numerics bit-identical.

#define B_    64
#define HW_   32
#define HP_   34
#define NLOC  1024
#define W_OST 9216u     // floats per o step
#define W_IST 589824u   // floats per i step
#define XT_BYTES  ((size_t)64*HP_*HP_*64*2)          //  9,469,952
#define WS_NEED   (XT_BYTES)
#define SCR_R 528       // shorts per role stripe: 512 + 16 pad (bank spread)

typedef __attribute__((ext_vector_type(8))) short short8;
typedef __attribute__((ext_vector_type(8))) unsigned short ushort8;
typedef __attribute__((ext_vector_type(4))) float floatx4;

static __device__ __forceinline__ unsigned short f2bf(float f) {
  __hip_bfloat16 h = __float2bfloat16(f);   // RNE
  return __builtin_bit_cast(unsigned short, h);
}

// unaligned-tolerant float4 load (weight rows are only 4B-aligned: loc*36B)
static __device__ __forceinline__ floatx4 ldf4u(const float* p) {
  floatx4 v; __builtin_memcpy(&v, p, 16); return v;
}

// ---------------------------------------------------------------------------
// Kernel 1: pad+transpose x[b][i][h][w] (fp32) -> xt[i][hh][ww][b] (bf16).
// (verified rounds 2-11, unchanged)
// ---------------------------------------------------------------------------
__global__ __launch_bounds__(256) void xpose_pad(const float* __restrict__ x,
                                                 unsigned short* __restrict__ xt) {
  int bid = blockIdx.x;                 // 64*34
  int i = bid / HP_, hh = bid % HP_;
  __shared__ float tile[B_ * 33];
  int t = threadIdx.x;
  bool interior = (hh >= 1 && hh <= HW_);
  if (interior) {
    int h = hh - 1, w = t & 31, bs = t >> 5;
    #pragma unroll
    for (int r = 0; r < 8; ++r) {
      int b = r * 8 + bs;
      tile[b * 33 + w] = x[(((size_t)b * 64 + i) * HW_ + h) * HW_ + w];
    }
  }
  __syncthreads();
  int b = t & 63, wsb = t >> 6;
  size_t base = (size_t)(i * HP_ + hh) * HP_ * B_;
  #pragma unroll
  for (int s = 0; s < 9; ++s) {
    int ww = s * 4 + wsb;
    if (ww < HP_) {
      float v = 0.f;
      if (interior && ww >= 1 && ww <= HW_) v = tile[b * 33 + (ww - 1)];
      xt[base + (size_t)ww * B_ + b] = f2bf(v);
    }
  }
}

// ---------------------------------------------------------------------------
// Kernel 2: fused im2col + GEMM, o-half split, direct per-lane B loads.
// Block = 4 consecutive locs x 32 o's, 256 thr = 4 waves; wave = ll (loc).
// LDS: Bs 16K + scr4 16.9K = 32.9K. Wave-private only; no barriers.
// ---------------------------------------------------------------------------
__global__ __launch_bounds__(256, 2) void lc2d_fused(
    const unsigned short* __restrict__ xt,
    const float* __restrict__ wsrc,
    const float* __restrict__ bias,
    float* __restrict__ out) {
  __shared__ __align__(16) unsigned short Bs[16 * 64 * 8];     // 16 KB (kk=8)
  __shared__ __align__(16) unsigned short scr4[4][4 * SCR_R];  // 16.9 KB

  const int bid   = blockIdx.x;                    // 512 blocks
  const int lt    = ((bid & 7) << 6) | (bid >> 3); // XCD-grouped tile id
  const int ohalf = lt & 1;
  const int loc0  = (lt >> 1) << 2;                // loc0 % 4 == 0
  const int tid   = threadIdx.x;
  const int lane  = tid & 63;
  const int ll    = tid >> 6;                      // wave = loc index 0..3
  const int loc   = loc0 + ll;
  const int hblk  = loc >> 5, wblk = loc & 31;
  const int col   = lane & 15;
  const int quad  = lane >> 4;
  const int o_0   = ohalf * 32 + col;              // nt=0 -> o_0, nt=1 -> +16

  floatx4 acc[4][2];
  {
    float b0 = bias[(unsigned)o_0 * 1024u + (unsigned)loc];
    float b1 = bias[(unsigned)(o_0 + 16) * 1024u + (unsigned)loc];
    #pragma unroll
    for (int mt = 0; mt < 4; ++mt) {
      acc[mt][0] = (floatx4){b0, b0, b0, b0};
      acc[mt][1] = (floatx4){b1, b1, b1, b1};
    }
  }

  // ---- B side: per-lane direct loads. Lane's row base for nt=0:
  //      w[i][o_0][loc][*] with i = 4c+quad; nt=1 adds 16*W_OST.
  const unsigned bbase0 = (unsigned)quad * W_IST + (unsigned)o_0 * W_OST
                        + (unsigned)loc * 9u;
  auto loadB = [&](int c, floatx4 &f0a, floatx4 &f0b, float &s0,
                   floatx4 &f1a, floatx4 &f1b, float &s1) {
    unsigned off = bbase0 + (unsigned)(4 * c) * W_IST;
    f0a = ldf4u(wsrc + off);
    f0b = ldf4u(wsrc + off + 4);
    s0  = wsrc[off + 8];
    unsigned off1 = off + 16u * W_OST;
    f1a = ldf4u(wsrc + off1);
    f1b = ldf4u(wsrc + off1 + 4);
    s1  = wsrc[off1 + 8];
  };
  auto cvtB = [&](floatx4 fa, floatx4 fb) -> ushort8 {
    ushort8 r;
    r[0] = f2bf(fa[0]); r[1] = f2bf(fa[1]); r[2] = f2bf(fa[2]); r[3] = f2bf(fa[3]);
    r[4] = f2bf(fb[0]); r[5] = f2bf(fb[1]); r[6] = f2bf(fb[2]); r[7] = f2bf(fb[3]);
    return r;
  };
  // kk=8 stash write (verified Bs layout; producer derivation in header)
  auto stashB = [&](int c, float s0, float s1) {
    int sc = c >> 3, cpr = c & 7;
    int sub = (cpr >> 1) * 16 + col;          // (k2>>3)*16 + oc
    int el  = (cpr & 1) * 4 + quad;           // k2 & 7
    Bs[(((ll * 2 + sc) * 2 + 0) * 64 + sub) * 8 + el] = f2bf(s0);
    Bs[(((ll * 2 + sc) * 2 + 1) * 64 + sub) * 8 + el] = f2bf(s1);
  };

  // ---- A side: xt load + 4-role scr + direct reg gather (verified r10/r11)
  auto xtLoad = [&](int t, int q) -> ushort8 {
    int i, kh, kw;
    if (t < 16) {
      i = (t << 2) + q;
      int kk = lane >> 3;                      // 0..7
      kh = kk / 3; kw = kk - kh * 3;
    } else {
      i = ((t - 16) << 5) + (q << 3) + (lane >> 3);
      kh = 2; kw = 2;
    }
    return *(const ushort8*)(xt +
        (((unsigned)i * HP_ + (unsigned)(hblk + kh)) * HP_ + (unsigned)(wblk + kw)) * 64u
        + ((unsigned)(lane & 7) << 3));
  };
  auto buildA = [&](ushort8 v0, ushort8 v1, ushort8 v2, ushort8 v3,
                    ushort8 &a0, ushort8 &a1, ushort8 &a2, ushort8 &a3) {
    *(ushort8*)&scr4[ll][0 * SCR_R + (lane << 3)] = v0;
    *(ushort8*)&scr4[ll][1 * SCR_R + (lane << 3)] = v1;
    *(ushort8*)&scr4[ll][2 * SCR_R + (lane << 3)] = v2;
    *(ushort8*)&scr4[ll][3 * SCR_R + (lane << 3)] = v3;
    __asm__ volatile("s_waitcnt lgkmcnt(0)" ::: "memory");
    const int rb = (lane >> 4) * SCR_R + (lane & 15);
    #pragma unroll
    for (int j = 0; j < 8; ++j) {
      a0[j] = scr4[ll][rb + j * 64 +  0];
      a1[j] = scr4[ll][rb + j * 64 + 16];
      a2[j] = scr4[ll][rb + j * 64 + 32];
      a3[j] = scr4[ll][rb + j * 64 + 48];
    }
  };

  // ---- MFMA: 4 A-frags x 2 B-frags in regs (same call order as verified)
  auto doMFMA = [&](ushort8 a0, ushort8 a1, ushort8 a2, ushort8 a3,
                    ushort8 b0, ushort8 b1) {
    acc[0][0] = __builtin_amdgcn_mfma_f32_16x16x32_bf16(
        __builtin_bit_cast(short8, a0), __builtin_bit_cast(short8, b0), acc[0][0], 0, 0, 0);
    acc[1][0] = __builtin_amdgcn_mfma_f32_16x16x32_bf16(
        __builtin_bit_cast(short8, a1), __builtin_bit_cast(short8, b0), acc[1][0], 0, 0, 0);
    acc[2][0] = __builtin_amdgcn_mfma_f32_16x16x32_bf16(
        __builtin_bit_cast(short8, a2), __builtin_bit_cast(short8, b0), acc[2][0], 0, 0, 0);
    acc[3][0] = __builtin_amdgcn_mfma_f32_16x16x32_bf16(
        __builtin_bit_cast(short8, a3), __builtin_bit_cast(short8, b0), acc[3][0], 0, 0, 0);
    acc[0][1] = __builtin_amdgcn_mfma_f32_16x16x32_bf16(
        __builtin_bit_cast(short8, a0), __builtin_bit_cast(short8, b1), acc[0][1], 0, 0, 0);
    acc[1][1] = __builtin_amdgcn_mfma_f32_16x16x32_bf16(
        __builtin_bit_cast(short8, a1), __builtin_bit_cast(short8, b1), acc[1][1], 0, 0, 0);
    acc[2][1] = __builtin_amdgcn_mfma_f32_16x16x32_bf16(
        __builtin_bit_cast(short8, a2), __builtin_bit_cast(short8, b1), acc[2][1], 0, 0, 0);
    acc[3][1] = __builtin_amdgcn_mfma_f32_16x16x32_bf16(
        __builtin_bit_cast(short8, a3), __builtin_bit_cast(short8, b1), acc[3][1], 0, 0, 0);
  };

  // ---- prologue: chunk 0 inputs in flight
  floatx4 cf0a, cf0b, cf1a, cf1b; float cs0, cs1;     // current B
  floatx4 nf0a, nf0b, nf1a, nf1b; float ns0, ns1;     // next B
  loadB(0, cf0a, cf0b, cs0, cf1a, cf1b, cs1);
  ushort8 xv0 = xtLoad(0, 0), xv1 = xtLoad(0, 1);
  ushort8 xv2 = xtLoad(0, 2), xv3 = xtLoad(0, 3);

  // ---- main loop c = 0..15 (no barriers; depth-1 prefetch of B and xt)
  #pragma unroll 1
  for (int c = 0; c < 16; ++c) {
    ushort8 nx0 = xtLoad(c + 1, 0), nx1 = xtLoad(c + 1, 1);
    ushort8 nx2 = xtLoad(c + 1, 2), nx3 = xtLoad(c + 1, 3);
    if (c < 15) loadB(c + 1, nf0a, nf0b, ns0, nf1a, nf1b, ns1);
    ushort8 b0 = cvtB(cf0a, cf0b);
    ushort8 b1 = cvtB(cf1a, cf1b);
    stashB(c, cs0, cs1);
    ushort8 a0, a1, a2, a3;
    buildA(xv0, xv1, xv2, xv3, a0, a1, a2, a3);
    doMFMA(a0, a1, a2, a3, b0, b1);
    cf0a = nf0a; cf0b = nf0b; cs0 = ns0;
    cf1a = nf1a; cf1b = nf1b; cs1 = ns1;
    xv0 = nx0; xv1 = nx1; xv2 = nx2; xv3 = nx3;
  }

  // ---- stash chunks (kk=8): c = 16, 17; B from Bs (wave-private RAW,
  //      ordered by lgkmcnt — no barrier needed)
  __asm__ volatile("s_waitcnt lgkmcnt(0)" ::: "memory");
  {
    ushort8 nx0 = xtLoad(17, 0), nx1 = xtLoad(17, 1);
    ushort8 nx2 = xtLoad(17, 2), nx3 = xtLoad(17, 3);
    ushort8 a0, a1, a2, a3;
    buildA(xv0, xv1, xv2, xv3, a0, a1, a2, a3);
    {
      int boff = (ll << 1) << 1;                              // sc=0
      ushort8 b0 = *(const ushort8*)(&Bs[0] + (size_t)((boff + 0) * 64 + lane) * 8);
      ushort8 b1 = *(const ushort8*)(&Bs[0] + (size_t)((boff + 1) * 64 + lane) * 8);
      doMFMA(a0, a1, a2, a3, b0, b1);
    }
    buildA(nx0, nx1, nx2, nx3, a0, a1, a2, a3);
    {
      int boff = ((ll << 1) + 1) << 1;                        // sc=1
      ushort8 b0 = *(const ushort8*)(&Bs[0] + (size_t)((boff + 0) * 64 + lane) * 8);
      ushort8 b1 = *(const ushort8*)(&Bs[0] + (size_t)((boff + 1) * 64 + lane) * 8);
      doMFMA(a0, a1, a2, a3, b0, b1);
    }
  }

  // ---- epilogue: D mapping col=o=lane&15, row=b = mt*16 + quad*4 + r (verified)
  #pragma unroll
  for (int mt = 0; mt < 4; ++mt) {
    int b = mt * 16 + quad * 4;
    #pragma unroll
    for (int r = 0; r < 4; ++r) {
      out[((unsigned)(b + r) * 64u + (unsigned)o_0) * 1024u + (unsigned)loc] = acc[mt][0][r];
      out[((unsigned)(b + r) * 64u + (unsigned)(o_0 + 16)) * 1024u + (unsigned)loc] = acc[mt][1][r];
    }
  }
}

// ---------------------------------------------------------------------------
// Fallback (tiny ws): fp32, direct x reads (round 1, correct for any ws).
// ---------------------------------------------------------------------------
__global__ __launch_bounds__(256, 4) void lc2d_fallback(
    const float* __restrict__ x, const float* __restrict__ weight,
    const float* __restrict__ bias, float* __restrict__ out) {
  int t0 = blockIdx.x;
  int loc = ((t0 & 7) << 7) | (t0 >> 3);
  int h = loc >> 5, w = loc & 31;
  int tid = threadIdx.x;
  int b = tid & 63;
  int o0 = (tid >> 6) * 16;
  __shared__ float As[72 * 64];
  float acc[16];
  #pragma unroll
  for (int j = 0; j < 16; ++j) acc[j] = bias[(size_t)(o0 + j) * NLOC + loc];
  for (int ic = 0; ic < 8; ++ic) {
    __syncthreads();
    #pragma unroll
    for (int s = 0; s < 18; ++s) {
      int f = s * 256 + tid;
      int k = f >> 6, lb = f & 63;
      int kk = k >> 3, isub = k & 7;
      int i = ic * 8 + isub;
      int kh = kk / 3, kw = kk - kh * 3;
      int hh = h + kh - 1, ww = w + kw - 1;
      float v = (hh >= 0 && hh < HW_ && ww >= 0 && ww < HW_)
                  ? x[(((size_t)lb * 64 + i) * HW_ + hh) * HW_ + ww] : 0.f;
      As[k * 64 + lb] = v;
    }
    __syncthreads();
    #pragma unroll 1
    for (int isub = 0; isub < 8; ++isub) {
      const float* wp = weight + (size_t)(ic * 8 + isub) * W_IST
                               + (size_t)o0 * W_OST + loc * 9;
      #pragma unroll
      for (int kk = 0; kk < 9; ++kk) {
        float a = As[(kk * 8 + isub) * 64 + b];
        #pragma unroll
        for (int j = 0; j < 16; ++j)
          acc[j] = fmaf(a, wp[(size_t)j * W_OST + kk], acc[j]);
      }
    }
  }
  size_t ob = ((size_t)b * 64 + o0) * NLOC + loc;
  #pragma unroll
  for (int j = 0; j < 16; ++j) out[ob + (size_t)j * NLOC] = acc[j];
}

// ---------------------------------------------------------------------------
extern "C" void kernel_launch(void* const* d_in, const int* in_sizes, int n_in,
                              void* d_out, int out_size, void* d_ws, size_t ws_size,
                              hipStream_t stream) {
  const float* x  = (const float*)d_in[0];
  const float* wt = (const float*)d_in[1];
  const float* bs = (const float*)d_in[2];
  float* out = (float*)d_out;

  if (ws_size >= WS_NEED) {
    unsigned short* xtb = (unsigned short*)d_ws;
    xpose_pad<<<64 * HP_, 256, 0, stream>>>(x, xtb);
    lc2d_fused<<<512, 256, 0, stream>>>(xtb, wt, bs, out);
  } else {
    lc2d_fallback<<<NLOC, 256, 0, stream>>>(x, wt, bs, out);
  }
}